// Round 14
// baseline (232.664 us; speedup 1.0000x reference)
//
#include <hip/hip_runtime.h>
#include <hip/hip_bf16.h>
#include <cstdint>
#include <cstddef>

// B=2, S=4096, HID=512, H=8, D_K=64.
// v24 = v23 + T5 (s_setprio around attn MFMA clusters). v23 components:
//   attn v22 (hand-unrolled 3-buffer rotation, 96.5us proven),
//   proj/oproj v21 (rolled BK=32 3-deep counted vmcnt),
//   cvt (q/k/v+weights+mask fused), combine.
// T5 mechanism: 2 independent blocks/CU -> waves at different phases;
// priority hint keeps matrix pipe fed while other block's waves issue
// stage/ds traffic (m191: +4-7% on attn; null only on lockstep GEMM).

namespace {

constexpr int kB = 2, kS = 4096, kHid = 512, kH = 8, kDk = 64;
constexpr int kBH = kB * kH;   // 16
constexpr int kM = kB * kS;    // 8192

typedef __attribute__((ext_vector_type(8))) short short8;
typedef __attribute__((ext_vector_type(2))) float float2v;
typedef __attribute__((ext_vector_type(4))) float floatx4;
typedef __attribute__((ext_vector_type(16))) float floatx16;
typedef __attribute__((ext_vector_type(4))) unsigned int uintx4;
typedef unsigned short u16;

__device__ __forceinline__ u16 bf16rne(float f) {
    uint32_t u = __float_as_uint(f);
    u += 0x7fffu + ((u >> 16) & 1u);
    return (u16)(u >> 16);
}
__device__ __forceinline__ uint32_t pk2(float lo, float hi) {
#if __has_builtin(__builtin_amdgcn_cvt_pk_bf16_f32)
    typedef __attribute__((ext_vector_type(2))) __bf16 bf2;
    bf2 h = __builtin_amdgcn_cvt_pk_bf16_f32(lo, hi);
    return __builtin_bit_cast(uint32_t, h);
#else
    return ((uint32_t)bf16rne(hi) << 16) | (uint32_t)bf16rne(lo);
#endif
}
__device__ __forceinline__ float fexp2(float x) {
#if __has_builtin(__builtin_amdgcn_exp2f)
    return __builtin_amdgcn_exp2f(x);
#else
    return exp2f(x);
#endif
}
__device__ __forceinline__ float bf2f(u16 v) {
    return __uint_as_float((uint32_t)v << 16);
}
__device__ __forceinline__ void plswap(uint32_t& a, uint32_t& b) {
#if __has_builtin(__builtin_amdgcn_permlane32_swap)
    typedef __attribute__((ext_vector_type(2))) unsigned int uint2v;
    uint2v r = __builtin_amdgcn_permlane32_swap(a, b, false, false);
    a = r[0]; b = r[1];
#else
    asm volatile("v_permlane32_swap_b32 %0, %1" : "+v"(a), "+v"(b));
#endif
}
__device__ __forceinline__ void gload16(const void* g, void* l) {
    __builtin_amdgcn_global_load_lds(
        (const __attribute__((address_space(1))) void*)g,
        (__attribute__((address_space(3))) void*)l, 16, 0, 0);
}

#define WAITV(n) do { \
    asm volatile("s_waitcnt vmcnt(" #n ")" ::: "memory"); \
    __builtin_amdgcn_s_barrier(); \
    __builtin_amdgcn_sched_barrier(0); \
} while (0)

// ---- fused f32->bf16: q/k/v, weights, and mask->bias -----------------------
__global__ __launch_bounds__(256) void cvt_qw(const float* __restrict__ q,
    const float* __restrict__ k, const float* __restrict__ v,
    const float* __restrict__ w0, const float* __restrict__ w1,
    const float* __restrict__ w2, const float* __restrict__ w3,
    const int* __restrict__ mask,
    u16* __restrict__ xall, u16* __restrict__ wall, float* __restrict__ fb) {
    const int bx = blockIdx.x;
    if (bx < 12288) {           // q/k/v: 3 x 4096 blocks
        int z = bx >> 12;
        size_t i = (size_t)(bx & 4095) * 256 + threadIdx.x;
        const float* src = z == 0 ? q : (z == 1 ? k : v);
        float4 f = ((const float4*)src)[i];
        ushort4 o;
        o.x = bf16rne(f.x); o.y = bf16rne(f.y);
        o.z = bf16rne(f.z); o.w = bf16rne(f.w);
        ((ushort4*)(xall + (size_t)z * kM * kHid))[i] = o;
    } else if (bx < 13312) {    // weights: 4 x 256 blocks
        int r = bx - 12288;
        int z = r >> 8;
        size_t i = (size_t)(r & 255) * 256 + threadIdx.x;
        const float* src = z == 0 ? w0 : (z == 1 ? w1 : (z == 2 ? w2 : w3));
        float sc = (z == 0)
            ? (float)(1.4426950408889634 / (6.0 * 0.6931471805599453))  // log2e/ln64
            : 1.0f;
        float4 f = ((const float4*)src)[i];
        ushort4 o;
        o.x = bf16rne(f.x * sc); o.y = bf16rne(f.y * sc);
        o.z = bf16rne(f.z * sc); o.w = bf16rne(f.w * sc);
        ((ushort4*)(wall + (size_t)z * kHid * kHid))[i] = o;
    } else {                    // mask -> bias: 32 blocks (8192 ints)
        int i = (bx - 13312) * 256 + threadIdx.x;
        fb[i] = mask[i] ? 0.0f : -1e30f;
    }
}

// ---- QKV projection: out = x @ W^T; block 128x128, wave 64x64 --------------
// BK=32, 3-deep counted-vmcnt pipeline (rolled rotation; v21-proven).
__global__ __launch_bounds__(256, 3) void proj(const u16* __restrict__ xall,
    const u16* __restrict__ wall, u16* __restrict__ qp, u16* __restrict__ kp,
    u16* __restrict__ vt) {
    union PS {
        struct { u16 A[3][128][32]; u16 B[3][128][32]; } s;  // 49152 B
        float smt[4][16][68];                                 // 17408 B
    };
    __shared__ __align__(16) PS sm;
    const int z = blockIdx.z;
    const u16* x = xall + (size_t)z * kM * kHid;
    const u16* w = wall + (size_t)z * kHid * kHid;
    const int tid = threadIdx.x;
    const int wv = tid >> 6, lane = tid & 63;
    const int quad = lane >> 4, l16 = lane & 15;
    const int mb = blockIdx.x * 128, nb = blockIdx.y * 128;
    const int mw = (wv >> 1) * 64, nw = (wv & 1) * 64;
    floatx4 acc[4][4] = {};

    const int srow = lane >> 2;                       // 0..15
    const int scol = ((lane & 3) ^ (srow & 3)) * 8;   // swizzled src col (u16)
    const u16* pA = x + (size_t)(mb + wv * 16 + srow) * kHid + scol;
    const u16* pB = w + (size_t)(nb + wv * 16 + srow) * kHid + scol;
    auto stage = [&](int buf) {
        gload16(pA,                     &sm.s.A[buf][wv * 16][0]);
        gload16(pA + (size_t)64 * kHid, &sm.s.A[buf][64 + wv * 16][0]);
        gload16(pB,                     &sm.s.B[buf][wv * 16][0]);
        gload16(pB + (size_t)64 * kHid, &sm.s.B[buf][64 + wv * 16][0]);
        pA += 32; pB += 32;             // advance one BK=32 step
    };
    auto compute = [&](int buf) {
        short8 a[4], bt[4];
#pragma unroll
        for (int i = 0; i < 4; i++)
            a[i] = *(const short8*)&sm.s.A[buf][mw + i * 16 + l16]
                    [(quad ^ (l16 & 3)) * 8];
#pragma unroll
        for (int t = 0; t < 4; t++)
            bt[t] = *(const short8*)&sm.s.B[buf][nw + t * 16 + l16]
                    [(quad ^ (l16 & 3)) * 8];
        if (z == 2) {
            // swapped operands: D[n][m] (col = m = s) for coalesced V^T
#pragma unroll
            for (int i = 0; i < 4; i++)
#pragma unroll
            for (int t = 0; t < 4; t++)
                acc[i][t] = __builtin_amdgcn_mfma_f32_16x16x32_bf16(bt[t], a[i], acc[i][t], 0, 0, 0);
        } else {
#pragma unroll
            for (int i = 0; i < 4; i++)
#pragma unroll
            for (int t = 0; t < 4; t++)
                acc[i][t] = __builtin_amdgcn_mfma_f32_16x16x32_bf16(a[i], bt[t], acc[i][t], 0, 0, 0);
        }
    };

    stage(0);
    stage(1);
    // 16 K-tiles; invariant at iter top after vmcnt(4): group(t) retired,
    // group(t+1) in flight. One barrier per tile (3-buf rotation).
    for (int t = 0; t < 14; ++t) {
        WAITV(4);
        stage((t + 2) % 3);
        compute(t % 3);
    }
    WAITV(4);
    compute(2);                         // tile 14
    WAITV(0);
    compute(0);                         // tile 15
    __syncthreads();   // staging reads done before smt overlay

    const int mbw = mb + mw, nbw = nb + nw;
    if (z < 2) {
        u16* dst = (z == 0) ? qp : kp;
        const int row16 = lane >> 2, cseg = (lane & 3) * 16;
#pragma unroll
        for (int i = 0; i < 4; i++) {
#pragma unroll
            for (int t = 0; t < 4; t++)
#pragma unroll
            for (int r = 0; r < 4; r++)
                sm.smt[wv][quad * 4 + r][t * 16 + l16] = acc[i][t][r];
            __builtin_amdgcn_wave_barrier();
            const float* rp = &sm.smt[wv][row16][cseg];
            float4 f0 = *(const float4*)(rp);
            float4 f1 = *(const float4*)(rp + 4);
            float4 f2 = *(const float4*)(rp + 8);
            float4 f3 = *(const float4*)(rp + 12);
            uint4 o0, o1;
            o0.x = pk2(f0.x, f0.y); o0.y = pk2(f0.z, f0.w);
            o0.z = pk2(f1.x, f1.y); o0.w = pk2(f1.z, f1.w);
            o1.x = pk2(f2.x, f2.y); o1.y = pk2(f2.z, f2.w);
            o1.z = pk2(f3.x, f3.y); o1.w = pk2(f3.z, f3.w);
            u16* dp = dst + (size_t)(mbw + i * 16 + row16) * kHid + nbw + cseg;
            *(uint4*)dp = o0;
            *(uint4*)(dp + 8) = o1;
            __builtin_amdgcn_wave_barrier();
        }
    } else {
        // V^T epilogue: per t-phase, 16(d) x 64(s) via LDS, coalesced rows.
        const int b = mbw >> 12, s0 = mbw & (kS - 1);
        const int row16 = lane >> 2, cseg = (lane & 3) * 16;
#pragma unroll
        for (int t = 0; t < 4; t++) {
#pragma unroll
            for (int i = 0; i < 4; i++)
#pragma unroll
            for (int r = 0; r < 4; r++)
                sm.smt[wv][quad * 4 + r][i * 16 + l16] = acc[i][t][r];
            __builtin_amdgcn_wave_barrier();
            const float* rp = &sm.smt[wv][row16][cseg];
            float4 f0 = *(const float4*)(rp);
            float4 f1 = *(const float4*)(rp + 4);
            float4 f2 = *(const float4*)(rp + 8);
            float4 f3 = *(const float4*)(rp + 12);
            uint4 o0, o1;
            o0.x = pk2(f0.x, f0.y); o0.y = pk2(f0.z, f0.w);
            o0.z = pk2(f1.x, f1.y); o0.w = pk2(f1.z, f1.w);
            o1.x = pk2(f2.x, f2.y); o1.y = pk2(f2.z, f2.w);
            o1.z = pk2(f3.x, f3.y); o1.w = pk2(f3.z, f3.w);
            const int n = nbw + t * 16 + row16;
            const int h = n >> 6, d = n & (kDk - 1);
            u16* dp = vt + ((size_t)(b * kH + h) * kDk + d) * kS + s0 + cseg;
            *(uint4*)dp = o0;
            *(uint4*)(dp + 8) = o1;
            __builtin_amdgcn_wave_barrier();
        }
    }
}

// ---- flash attention v24 (v22 + setprio around MFMA clusters) --------------
// 512 blocks x 256 thr; wave owns 64 q (2 q-tiles of 32); split-K kz=0/1.
// 3-deep LDS staging (K/V/bias), raw barriers, counted vmcnt(5), unrolled.
__global__ __launch_bounds__(256, 2) void attn(const u16* __restrict__ qp,
    const u16* __restrict__ kp, const u16* __restrict__ vt,
    const float* __restrict__ fbias, u16* __restrict__ ows,
    float* __restrict__ rsws) {
    union SmT {
        struct { u16 K[3][64][64]; u16 V[3][64][64]; float B[3][256]; } s;  // 52224 B
        float ep[4][32][33];                                                 // 16896 B
    };
    __shared__ __align__(16) SmT sm;
    const int tid = threadIdx.x;
    const int wv = tid >> 6, l = tid & 63;
    const int hf = l >> 5, q32 = l & 31, l7 = l & 7;
    // XCD-aware decode: 512 = 8 xcd x (2 bh x 16 qb x 2 kz)
    const int wg = blockIdx.x;
    const int bh = ((wg & 7) << 1) | ((wg >> 3) & 1);
    const int qb = (wg >> 4) & 15;
    const int kz = wg >> 8;
    const int b = bh >> 3, h = bh & 7;
    const int qbase = qb * 256 + wv * 64;
    const u16* Qb = qp + (size_t)b * kS * kHid + h * 64;   // [s][512] + h*64
    const u16* Kb = kp + (size_t)b * kS * kHid + h * 64;
    const u16* Vb = vt + (size_t)bh * kDk * kS;            // [d][s]
    const float* fm = fbias + b * kS;

    // Q frags: row = qbase+qt*32+q32, k-chunk m*16 + hf*8
    short8 qf[2][4];
#pragma unroll
    for (int qt = 0; qt < 2; qt++)
#pragma unroll
    for (int m = 0; m < 4; m++)
        qf[qt][m] = *(const short8*)(Qb + (size_t)(qbase + qt * 32 + q32) * kHid + m * 16 + hf * 8);

    floatx16 O[2][2] = {};   // [qt][d-half], C-layout
    float rs[2] = {0.0f, 0.0f};

    const int srow = l >> 3;
    const int pcol = (l7 ^ srow) * 8;
    const u16* pK = Kb + (size_t)(kz * 64 + wv * 8 + srow) * kHid + pcol;
    const u16* pV = Vb + (size_t)(wv * 8 + srow) * kS + kz * 64 + pcol;
    const float* pB = fm + kz * 64 + (l & 15) * 4;
    auto stage = [&](int buf) {
        gload16(pK,                     &sm.s.K[buf][wv * 8][0]);
        gload16(pK + (size_t)32 * kHid, &sm.s.K[buf][wv * 8 + 32][0]);
        gload16(pV,                     &sm.s.V[buf][wv * 8][0]);
        gload16(pV + (size_t)32 * kS,   &sm.s.V[buf][wv * 8 + 32][0]);
        gload16(pB,                     &sm.s.B[buf][0]);
        pK += (size_t)128 * kHid;      // 2 key-tiles (split-K=2 stride)
        pV += 128;
        pB += 128;
    };

    auto compute = [&](int buf) {
#pragma unroll
        for (int ks = 0; ks < 2; ++ks) {
            short8 kf[4];
#pragma unroll
            for (int m = 0; m < 4; m++)
                kf[m] = *(const short8*)&sm.s.K[buf][ks * 32 + q32][((2 * m + hf) ^ l7) * 8];
            short8 vf[2][2];
#pragma unroll
            for (int ds = 0; ds < 2; ds++)
#pragma unroll
            for (int tt = 0; tt < 2; tt++)
                vf[ds][tt] = *(const short8*)&sm.s.V[buf][ds * 32 + q32][((ks * 4 + tt * 2 + hf) ^ l7) * 8];
            // bias from LDS (broadcast reads; key = (r&3)+8*(r>>2)+4*hf)
            const float* bb = &sm.s.B[buf][ks * 32 + 4 * hf];
            float4 g0 = *(const float4*)(bb);
            float4 g1 = *(const float4*)(bb + 8);
            float4 g2 = *(const float4*)(bb + 16);
            float4 g3 = *(const float4*)(bb + 24);
#pragma unroll
            for (int qt = 0; qt < 2; ++qt) {
                floatx16 st;
                st[0] = g0.x;  st[1] = g0.y;  st[2] = g0.z;  st[3] = g0.w;
                st[4] = g1.x;  st[5] = g1.y;  st[6] = g1.z;  st[7] = g1.w;
                st[8] = g2.x;  st[9] = g2.y;  st[10] = g2.z; st[11] = g2.w;
                st[12] = g3.x; st[13] = g3.y; st[14] = g3.z; st[15] = g3.w;
                // T5: favor this wave while it feeds the matrix pipe
                __builtin_amdgcn_s_setprio(1);
#pragma unroll
                for (int m = 0; m < 4; m++)
                    st = __builtin_amdgcn_mfma_f32_32x32x16_bf16(kf[m], qf[qt][m], st, 0, 0, 0);
                __builtin_amdgcn_s_setprio(0);
                float xx[16];
#pragma unroll
                for (int r = 0; r < 16; r++) xx[r] = fexp2(st[r]);
                float2v a0 = {xx[0], xx[1]},  a1 = {xx[2], xx[3]};
                float2v a2 = {xx[4], xx[5]},  a3 = {xx[6], xx[7]};
                float2v a4 = {xx[8], xx[9]},  a5 = {xx[10], xx[11]};
                float2v a6 = {xx[12], xx[13]}, a7 = {xx[14], xx[15]};
                a0 += a1; a2 += a3; a4 += a5; a6 += a7;
                a0 += a2; a4 += a6;
                a0 += a4;
                rs[qt] += a0[0] + a0[1];
                uint32_t w00 = pk2(xx[0], xx[1]),   w01 = pk2(xx[2], xx[3]);
                uint32_t w10 = pk2(xx[4], xx[5]),   w11 = pk2(xx[6], xx[7]);
                uint32_t w20 = pk2(xx[8], xx[9]),   w21 = pk2(xx[10], xx[11]);
                uint32_t w30 = pk2(xx[12], xx[13]), w31 = pk2(xx[14], xx[15]);
                plswap(w00, w10); plswap(w01, w11);
                plswap(w20, w30); plswap(w21, w31);
                uintx4 t0 = {w00, w01, w10, w11};
                uintx4 t1 = {w20, w21, w30, w31};
                short8 bf0 = __builtin_bit_cast(short8, t0);
                short8 bf1 = __builtin_bit_cast(short8, t1);
                __builtin_amdgcn_s_setprio(1);
                O[qt][0] = __builtin_amdgcn_mfma_f32_32x32x16_bf16(vf[0][0], bf0, O[qt][0], 0, 0, 0);
                O[qt][0] = __builtin_amdgcn_mfma_f32_32x32x16_bf16(vf[0][1], bf1, O[qt][0], 0, 0, 0);
                O[qt][1] = __builtin_amdgcn_mfma_f32_32x32x16_bf16(vf[1][0], bf0, O[qt][1], 0, 0, 0);
                O[qt][1] = __builtin_amdgcn_mfma_f32_32x32x16_bf16(vf[1][1], bf1, O[qt][1], 0, 0, 0);
                __builtin_amdgcn_s_setprio(0);
            }
        }
    };

    stage(0);
    stage(1);
    // tiles 0..29 hand-unrolled x3; stage tiles 2..31; then peel 30/31.
#pragma unroll 1
    for (int t3 = 0; t3 < 10; ++t3) {
        WAITV(5); stage(2); compute(0);   // t = 3k
        WAITV(5); stage(0); compute(1);   // t = 3k+1
        WAITV(5); stage(1); compute(2);   // t = 3k+2
    }
    WAITV(5); compute(0);                 // tile 30
    WAITV(0); compute(1);                 // tile 31
    __syncthreads();                      // all K/V/B reads done before overlay

    // partial row-sums + partial O (raw, bf16) per q-tile
#pragma unroll
    for (int qt = 0; qt < 2; ++qt) {
        float r = rs[qt];
        r += __shfl_xor(r, 32);
        if (hf == 0)
            rsws[((size_t)kz * kBH + bh) * kS + qbase + qt * 32 + q32] = r;
        u16* Ob = ows + (((size_t)kz * kBH + bh) * kS + qbase + qt * 32) * kDk;
#pragma unroll
        for (int ds = 0; ds < 2; ds++) {
#pragma unroll
            for (int rr = 0; rr < 16; rr++)
                sm.ep[wv][q32][(rr & 3) + 8 * (rr >> 2) + 4 * hf] = O[qt][ds][rr];
            __builtin_amdgcn_wave_barrier();
            {
                const int qq = l >> 1, c0 = (l & 1) * 16;
                float f[16];
#pragma unroll
                for (int j = 0; j < 16; j++) f[j] = sm.ep[wv][qq][c0 + j];
                uint4 o0, o1;
                o0.x = pk2(f[0], f[1]);   o0.y = pk2(f[2], f[3]);
                o0.z = pk2(f[4], f[5]);   o0.w = pk2(f[6], f[7]);
                o1.x = pk2(f[8], f[9]);   o1.y = pk2(f[10], f[11]);
                o1.z = pk2(f[12], f[13]); o1.w = pk2(f[14], f[15]);
                u16* dp = Ob + (size_t)qq * kDk + ds * 32 + c0;
                *(uint4*)dp = o0;
                *(uint4*)(dp + 8) = o1;
            }
            __builtin_amdgcn_wave_barrier();
        }
    }
}

// ---- combine: out = (O_part0 + O_part1) / (rs0 + rs1), bf16 ---------------
__global__ __launch_bounds__(256) void combine(const u16* __restrict__ ows,
    const float* __restrict__ rsws, u16* __restrict__ xo) {
    size_t i = (size_t)blockIdx.x * 256 + threadIdx.x;   // 524288 total
    const int d8 = (int)(i & 7);
    const int s  = (int)((i >> 3) & (kS - 1));
    const int bh = (int)(i >> 15);
    const int b = bh >> 3, h = bh & 7;
    const size_t base = ((size_t)bh * kS + s) * kDk + d8 * 8;
    short8 a = *(const short8*)(ows + base);
    short8 c = *(const short8*)(ows + (size_t)kBH * kS * kDk + base);
    float r = rsws[(size_t)bh * kS + s] + rsws[(size_t)kBH * kS + (size_t)bh * kS + s];
    float inv = 1.0f / r;
    float e[8];
#pragma unroll
    for (int j = 0; j < 8; j++)
        e[j] = (bf2f((u16)a[j]) + bf2f((u16)c[j])) * inv;
    uint4 o;
    o.x = pk2(e[0], e[1]); o.y = pk2(e[2], e[3]);
    o.z = pk2(e[4], e[5]); o.w = pk2(e[6], e[7]);
    *(uint4*)(xo + ((size_t)b * kS + s) * kHid + h * 64 + d8 * 8) = o;
}

// ---- output projection: out = X @ Wo^T; 64x128 tile, BK=32 3-deep ----------
// (rolled rotation; v21-proven)
__global__ __launch_bounds__(256, 2) void oproj(const u16* __restrict__ x,
    const u16* __restrict__ w, float* __restrict__ out) {
    __shared__ __align__(16) u16 A[3][64][32];    // 12288 B
    __shared__ __align__(16) u16 Bt[3][128][32];  // 24576 B
    const int tid = threadIdx.x;
    const int wv = tid >> 6, lane = tid & 63;
    const int quad = lane >> 4, l16 = lane & 15;
    const int mb = blockIdx.x * 64, nb = blockIdx.y * 128;
    const int mw = (wv >> 1) * 32, nw = (wv & 1) * 64;
    floatx4 acc[2][4] = {};
    const int srow = lane >> 2;
    const int scol = ((lane & 3) ^ (srow & 3)) * 8;
    const u16* pA = x + (size_t)(mb + wv * 16 + srow) * kHid + scol;
    const u16* pB = w + (size_t)(nb + wv * 16 + srow) * kHid + scol;
    auto stage = [&](int buf) {
        gload16(pA,                     &A[buf][wv * 16][0]);
        gload16(pB,                     &Bt[buf][wv * 16][0]);
        gload16(pB + (size_t)64 * kHid, &Bt[buf][64 + wv * 16][0]);
        pA += 32; pB += 32;
    };
    auto compute = [&](int buf) {
        short8 a[2], bt[4];
#pragma unroll
        for (int i = 0; i < 2; i++)
            a[i] = *(const short8*)&A[buf][mw + i * 16 + l16][(quad ^ (l16 & 3)) * 8];
#pragma unroll
        for (int t = 0; t < 4; t++)
            bt[t] = *(const short8*)&Bt[buf][nw + t * 16 + l16][(quad ^ (l16 & 3)) * 8];
#pragma unroll
        for (int i = 0; i < 2; i++)
#pragma unroll
        for (int t = 0; t < 4; t++)
            acc[i][t] = __builtin_amdgcn_mfma_f32_16x16x32_bf16(a[i], bt[t], acc[i][t], 0, 0, 0);
    };

    stage(0);
    stage(1);
    for (int t = 0; t < 14; ++t) {
        WAITV(3);
        stage((t + 2) % 3);
        compute(t % 3);
    }
    WAITV(3);
    compute(2);                         // tile 14
    WAITV(0);
    compute(0);                         // tile 15

    const int mbw = mb + mw, nbw = nb + nw;
#pragma unroll
    for (int i = 0; i < 2; i++)
#pragma unroll
    for (int t = 0; t < 4; t++)
#pragma unroll
    for (int r = 0; r < 4; r++) {
        int m = mbw + i * 16 + quad * 4 + r;
        int n = nbw + t * 16 + l16;
        out[(size_t)m * kHid + n] = acc[i][t][r];
    }
}

} // namespace

extern "C" void kernel_launch(void* const* d_in, const int* in_sizes, int n_in,
                              void* d_out, int out_size, void* d_ws, size_t ws_size,
                              hipStream_t stream) {
    const float* q  = (const float*)d_in[0];
    const float* k  = (const float*)d_in[1];
    const float* v  = (const float*)d_in[2];
    const int* mask = (const int*)d_in[3];
    const float* w0 = (const float*)d_in[4];
    const float* w1 = (const float*)d_in[5];
    const float* w2 = (const float*)d_in[6];
    const float* w3 = (const float*)d_in[7];
    float* out = (float*)d_out;

    // ws (u16 units), ~52.4 MB:
    //   xall: 3*kM*kHid = 25.2 MB (bf16 q/k/v; reused as ows
    //         [2][16][4096][64] bf16 = 16.8 MB after proj)
    //   wall: 4*kHid*kHid = 2.1 MB (bf16 w0..w3; w0..w2 dead after proj ->
    //         rsws ([2][16][4096] f32, 512 KB); w3 stays live for oproj)
    //   qp, kp, vt: 8.4 MB each; xo (combine output) reuses qp after attn.
    // fbias (32 KB f32) lives in d_out scratch: written by cvt_qw, read by
    // attn, overwritten by oproj (which runs strictly after attn).
    u16* ws   = (u16*)d_ws;
    u16* xall = ws;
    u16* wall = xall + (size_t)3 * kM * kHid;
    u16* qp   = wall + (size_t)4 * kHid * kHid;
    u16* kp   = qp + (size_t)kBH * kS * kDk;
    u16* vt   = kp + (size_t)kBH * kS * kDk;
    u16* ows  = xall;
    float* rsws  = (float*)wall;
    float* fbias = out;
    u16* xo   = qp;

    dim3 blk(256);
    cvt_qw <<<dim3(13344), blk, 0, stream>>>(q, k, v, w0, w1, w2, w3, mask,
                                             xall, wall, fbias);
    proj   <<<dim3(kM / 128, kHid / 128, 3), blk, 0, stream>>>(xall, wall, qp, kp, vt);
    attn   <<<dim3(512), blk, 0, stream>>>(qp, kp, vt, fbias, ows, rsws);
    combine<<<dim3(2048), blk, 0, stream>>>(ows, rsws, xo);
    oproj  <<<dim3(kM / 64, kHid / 128), blk, 0, stream>>>(
        xo, wall + (size_t)3 * kHid * kHid, out);
}

// Round 15
// 222.086 us; speedup vs baseline: 1.0476x; 1.0476x over previous
//
#include <hip/hip_runtime.h>
#include <hip/hip_bf16.h>
#include <cstdint>
#include <cstddef>

// B=2, S=4096, HID=512, H=8, D_K=64.
// v25 = v23 (session best, 225.25us). R14's T5/setprio experiment REGRESSED
// attn 96.5->115us (barrier-locked waves: priority inversion against the
// other block's staging waves) -> reverted. Final configuration:
//   cvt (f32->bf16 q/k/v+weights, mask->bias in d_out scratch) ->
//   proj (BK=32 3-deep counted vmcnt, 3 blocks/CU resident) ->
//   attn v22 (split-K=2, 3-deep, vmcnt(5), hand-unrolled; 96.5us) ->
//   combine -> oproj (64x128, BK=32 3-deep).
// Resolved-negative for this problem: split-K>=3 (x3), setprio, fused
// oproj+combine, reg-staged cvt-in-proj, GEMM-body unroll.

namespace {

constexpr int kB = 2, kS = 4096, kHid = 512, kH = 8, kDk = 64;
constexpr int kBH = kB * kH;   // 16
constexpr int kM = kB * kS;    // 8192

typedef __attribute__((ext_vector_type(8))) short short8;
typedef __attribute__((ext_vector_type(2))) float float2v;
typedef __attribute__((ext_vector_type(4))) float floatx4;
typedef __attribute__((ext_vector_type(16))) float floatx16;
typedef __attribute__((ext_vector_type(4))) unsigned int uintx4;
typedef unsigned short u16;

__device__ __forceinline__ u16 bf16rne(float f) {
    uint32_t u = __float_as_uint(f);
    u += 0x7fffu + ((u >> 16) & 1u);
    return (u16)(u >> 16);
}
__device__ __forceinline__ uint32_t pk2(float lo, float hi) {
#if __has_builtin(__builtin_amdgcn_cvt_pk_bf16_f32)
    typedef __attribute__((ext_vector_type(2))) __bf16 bf2;
    bf2 h = __builtin_amdgcn_cvt_pk_bf16_f32(lo, hi);
    return __builtin_bit_cast(uint32_t, h);
#else
    return ((uint32_t)bf16rne(hi) << 16) | (uint32_t)bf16rne(lo);
#endif
}
__device__ __forceinline__ float fexp2(float x) {
#if __has_builtin(__builtin_amdgcn_exp2f)
    return __builtin_amdgcn_exp2f(x);
#else
    return exp2f(x);
#endif
}
__device__ __forceinline__ float bf2f(u16 v) {
    return __uint_as_float((uint32_t)v << 16);
}
__device__ __forceinline__ void plswap(uint32_t& a, uint32_t& b) {
#if __has_builtin(__builtin_amdgcn_permlane32_swap)
    typedef __attribute__((ext_vector_type(2))) unsigned int uint2v;
    uint2v r = __builtin_amdgcn_permlane32_swap(a, b, false, false);
    a = r[0]; b = r[1];
#else
    asm volatile("v_permlane32_swap_b32 %0, %1" : "+v"(a), "+v"(b));
#endif
}
__device__ __forceinline__ void gload16(const void* g, void* l) {
    __builtin_amdgcn_global_load_lds(
        (const __attribute__((address_space(1))) void*)g,
        (__attribute__((address_space(3))) void*)l, 16, 0, 0);
}

#define WAITV(n) do { \
    asm volatile("s_waitcnt vmcnt(" #n ")" ::: "memory"); \
    __builtin_amdgcn_s_barrier(); \
    __builtin_amdgcn_sched_barrier(0); \
} while (0)

// ---- fused f32->bf16: q/k/v, weights, and mask->bias -----------------------
__global__ __launch_bounds__(256) void cvt_qw(const float* __restrict__ q,
    const float* __restrict__ k, const float* __restrict__ v,
    const float* __restrict__ w0, const float* __restrict__ w1,
    const float* __restrict__ w2, const float* __restrict__ w3,
    const int* __restrict__ mask,
    u16* __restrict__ xall, u16* __restrict__ wall, float* __restrict__ fb) {
    const int bx = blockIdx.x;
    if (bx < 12288) {           // q/k/v: 3 x 4096 blocks
        int z = bx >> 12;
        size_t i = (size_t)(bx & 4095) * 256 + threadIdx.x;
        const float* src = z == 0 ? q : (z == 1 ? k : v);
        float4 f = ((const float4*)src)[i];
        ushort4 o;
        o.x = bf16rne(f.x); o.y = bf16rne(f.y);
        o.z = bf16rne(f.z); o.w = bf16rne(f.w);
        ((ushort4*)(xall + (size_t)z * kM * kHid))[i] = o;
    } else if (bx < 13312) {    // weights: 4 x 256 blocks
        int r = bx - 12288;
        int z = r >> 8;
        size_t i = (size_t)(r & 255) * 256 + threadIdx.x;
        const float* src = z == 0 ? w0 : (z == 1 ? w1 : (z == 2 ? w2 : w3));
        float sc = (z == 0)
            ? (float)(1.4426950408889634 / (6.0 * 0.6931471805599453))  // log2e/ln64
            : 1.0f;
        float4 f = ((const float4*)src)[i];
        ushort4 o;
        o.x = bf16rne(f.x * sc); o.y = bf16rne(f.y * sc);
        o.z = bf16rne(f.z * sc); o.w = bf16rne(f.w * sc);
        ((ushort4*)(wall + (size_t)z * kHid * kHid))[i] = o;
    } else {                    // mask -> bias: 32 blocks (8192 ints)
        int i = (bx - 13312) * 256 + threadIdx.x;
        fb[i] = mask[i] ? 0.0f : -1e30f;
    }
}

// ---- QKV projection: out = x @ W^T; block 128x128, wave 64x64 --------------
// BK=32, 3-deep counted-vmcnt pipeline (rolled rotation; v21-proven).
__global__ __launch_bounds__(256, 3) void proj(const u16* __restrict__ xall,
    const u16* __restrict__ wall, u16* __restrict__ qp, u16* __restrict__ kp,
    u16* __restrict__ vt) {
    union PS {
        struct { u16 A[3][128][32]; u16 B[3][128][32]; } s;  // 49152 B
        float smt[4][16][68];                                 // 17408 B
    };
    __shared__ __align__(16) PS sm;
    const int z = blockIdx.z;
    const u16* x = xall + (size_t)z * kM * kHid;
    const u16* w = wall + (size_t)z * kHid * kHid;
    const int tid = threadIdx.x;
    const int wv = tid >> 6, lane = tid & 63;
    const int quad = lane >> 4, l16 = lane & 15;
    const int mb = blockIdx.x * 128, nb = blockIdx.y * 128;
    const int mw = (wv >> 1) * 64, nw = (wv & 1) * 64;
    floatx4 acc[4][4] = {};

    const int srow = lane >> 2;                       // 0..15
    const int scol = ((lane & 3) ^ (srow & 3)) * 8;   // swizzled src col (u16)
    const u16* pA = x + (size_t)(mb + wv * 16 + srow) * kHid + scol;
    const u16* pB = w + (size_t)(nb + wv * 16 + srow) * kHid + scol;
    auto stage = [&](int buf) {
        gload16(pA,                     &sm.s.A[buf][wv * 16][0]);
        gload16(pA + (size_t)64 * kHid, &sm.s.A[buf][64 + wv * 16][0]);
        gload16(pB,                     &sm.s.B[buf][wv * 16][0]);
        gload16(pB + (size_t)64 * kHid, &sm.s.B[buf][64 + wv * 16][0]);
        pA += 32; pB += 32;             // advance one BK=32 step
    };
    auto compute = [&](int buf) {
        short8 a[4], bt[4];
#pragma unroll
        for (int i = 0; i < 4; i++)
            a[i] = *(const short8*)&sm.s.A[buf][mw + i * 16 + l16]
                    [(quad ^ (l16 & 3)) * 8];
#pragma unroll
        for (int t = 0; t < 4; t++)
            bt[t] = *(const short8*)&sm.s.B[buf][nw + t * 16 + l16]
                    [(quad ^ (l16 & 3)) * 8];
        if (z == 2) {
            // swapped operands: D[n][m] (col = m = s) for coalesced V^T
#pragma unroll
            for (int i = 0; i < 4; i++)
#pragma unroll
            for (int t = 0; t < 4; t++)
                acc[i][t] = __builtin_amdgcn_mfma_f32_16x16x32_bf16(bt[t], a[i], acc[i][t], 0, 0, 0);
        } else {
#pragma unroll
            for (int i = 0; i < 4; i++)
#pragma unroll
            for (int t = 0; t < 4; t++)
                acc[i][t] = __builtin_amdgcn_mfma_f32_16x16x32_bf16(a[i], bt[t], acc[i][t], 0, 0, 0);
        }
    };

    stage(0);
    stage(1);
    // 16 K-tiles; invariant at iter top after vmcnt(4): group(t) retired,
    // group(t+1) in flight. One barrier per tile (3-buf rotation).
    for (int t = 0; t < 14; ++t) {
        WAITV(4);
        stage((t + 2) % 3);
        compute(t % 3);
    }
    WAITV(4);
    compute(2);                         // tile 14
    WAITV(0);
    compute(0);                         // tile 15
    __syncthreads();   // staging reads done before smt overlay

    const int mbw = mb + mw, nbw = nb + nw;
    if (z < 2) {
        u16* dst = (z == 0) ? qp : kp;
        const int row16 = lane >> 2, cseg = (lane & 3) * 16;
#pragma unroll
        for (int i = 0; i < 4; i++) {
#pragma unroll
            for (int t = 0; t < 4; t++)
#pragma unroll
            for (int r = 0; r < 4; r++)
                sm.smt[wv][quad * 4 + r][t * 16 + l16] = acc[i][t][r];
            __builtin_amdgcn_wave_barrier();
            const float* rp = &sm.smt[wv][row16][cseg];
            float4 f0 = *(const float4*)(rp);
            float4 f1 = *(const float4*)(rp + 4);
            float4 f2 = *(const float4*)(rp + 8);
            float4 f3 = *(const float4*)(rp + 12);
            uint4 o0, o1;
            o0.x = pk2(f0.x, f0.y); o0.y = pk2(f0.z, f0.w);
            o0.z = pk2(f1.x, f1.y); o0.w = pk2(f1.z, f1.w);
            o1.x = pk2(f2.x, f2.y); o1.y = pk2(f2.z, f2.w);
            o1.z = pk2(f3.x, f3.y); o1.w = pk2(f3.z, f3.w);
            u16* dp = dst + (size_t)(mbw + i * 16 + row16) * kHid + nbw + cseg;
            *(uint4*)dp = o0;
            *(uint4*)(dp + 8) = o1;
            __builtin_amdgcn_wave_barrier();
        }
    } else {
        // V^T epilogue: per t-phase, 16(d) x 64(s) via LDS, coalesced rows.
        const int b = mbw >> 12, s0 = mbw & (kS - 1);
        const int row16 = lane >> 2, cseg = (lane & 3) * 16;
#pragma unroll
        for (int t = 0; t < 4; t++) {
#pragma unroll
            for (int i = 0; i < 4; i++)
#pragma unroll
            for (int r = 0; r < 4; r++)
                sm.smt[wv][quad * 4 + r][i * 16 + l16] = acc[i][t][r];
            __builtin_amdgcn_wave_barrier();
            const float* rp = &sm.smt[wv][row16][cseg];
            float4 f0 = *(const float4*)(rp);
            float4 f1 = *(const float4*)(rp + 4);
            float4 f2 = *(const float4*)(rp + 8);
            float4 f3 = *(const float4*)(rp + 12);
            uint4 o0, o1;
            o0.x = pk2(f0.x, f0.y); o0.y = pk2(f0.z, f0.w);
            o0.z = pk2(f1.x, f1.y); o0.w = pk2(f1.z, f1.w);
            o1.x = pk2(f2.x, f2.y); o1.y = pk2(f2.z, f2.w);
            o1.z = pk2(f3.x, f3.y); o1.w = pk2(f3.z, f3.w);
            const int n = nbw + t * 16 + row16;
            const int h = n >> 6, d = n & (kDk - 1);
            u16* dp = vt + ((size_t)(b * kH + h) * kDk + d) * kS + s0 + cseg;
            *(uint4*)dp = o0;
            *(uint4*)(dp + 8) = o1;
            __builtin_amdgcn_wave_barrier();
        }
    }
}

// ---- flash attention v22 (hand-unrolled rotation; 96.5us proven) -----------
// 512 blocks x 256 thr; wave owns 64 q (2 q-tiles of 32); split-K kz=0/1.
// 3-deep LDS staging (K/V/bias), raw barriers, counted vmcnt(5).
__global__ __launch_bounds__(256, 2) void attn(const u16* __restrict__ qp,
    const u16* __restrict__ kp, const u16* __restrict__ vt,
    const float* __restrict__ fbias, u16* __restrict__ ows,
    float* __restrict__ rsws) {
    union SmT {
        struct { u16 K[3][64][64]; u16 V[3][64][64]; float B[3][256]; } s;  // 52224 B
        float ep[4][32][33];                                                 // 16896 B
    };
    __shared__ __align__(16) SmT sm;
    const int tid = threadIdx.x;
    const int wv = tid >> 6, l = tid & 63;
    const int hf = l >> 5, q32 = l & 31, l7 = l & 7;
    // XCD-aware decode: 512 = 8 xcd x (2 bh x 16 qb x 2 kz)
    const int wg = blockIdx.x;
    const int bh = ((wg & 7) << 1) | ((wg >> 3) & 1);
    const int qb = (wg >> 4) & 15;
    const int kz = wg >> 8;
    const int b = bh >> 3, h = bh & 7;
    const int qbase = qb * 256 + wv * 64;
    const u16* Qb = qp + (size_t)b * kS * kHid + h * 64;   // [s][512] + h*64
    const u16* Kb = kp + (size_t)b * kS * kHid + h * 64;
    const u16* Vb = vt + (size_t)bh * kDk * kS;            // [d][s]
    const float* fm = fbias + b * kS;

    // Q frags: row = qbase+qt*32+q32, k-chunk m*16 + hf*8
    short8 qf[2][4];
#pragma unroll
    for (int qt = 0; qt < 2; qt++)
#pragma unroll
    for (int m = 0; m < 4; m++)
        qf[qt][m] = *(const short8*)(Qb + (size_t)(qbase + qt * 32 + q32) * kHid + m * 16 + hf * 8);

    floatx16 O[2][2] = {};   // [qt][d-half], C-layout
    float rs[2] = {0.0f, 0.0f};

    const int srow = l >> 3;
    const int pcol = (l7 ^ srow) * 8;
    const u16* pK = Kb + (size_t)(kz * 64 + wv * 8 + srow) * kHid + pcol;
    const u16* pV = Vb + (size_t)(wv * 8 + srow) * kS + kz * 64 + pcol;
    const float* pB = fm + kz * 64 + (l & 15) * 4;
    auto stage = [&](int buf) {
        gload16(pK,                     &sm.s.K[buf][wv * 8][0]);
        gload16(pK + (size_t)32 * kHid, &sm.s.K[buf][wv * 8 + 32][0]);
        gload16(pV,                     &sm.s.V[buf][wv * 8][0]);
        gload16(pV + (size_t)32 * kS,   &sm.s.V[buf][wv * 8 + 32][0]);
        gload16(pB,                     &sm.s.B[buf][0]);
        pK += (size_t)128 * kHid;      // 2 key-tiles (split-K=2 stride)
        pV += 128;
        pB += 128;
    };

    auto compute = [&](int buf) {
#pragma unroll
        for (int ks = 0; ks < 2; ++ks) {
            short8 kf[4];
#pragma unroll
            for (int m = 0; m < 4; m++)
                kf[m] = *(const short8*)&sm.s.K[buf][ks * 32 + q32][((2 * m + hf) ^ l7) * 8];
            short8 vf[2][2];
#pragma unroll
            for (int ds = 0; ds < 2; ds++)
#pragma unroll
            for (int tt = 0; tt < 2; tt++)
                vf[ds][tt] = *(const short8*)&sm.s.V[buf][ds * 32 + q32][((ks * 4 + tt * 2 + hf) ^ l7) * 8];
            // bias from LDS (broadcast reads; key = (r&3)+8*(r>>2)+4*hf)
            const float* bb = &sm.s.B[buf][ks * 32 + 4 * hf];
            float4 g0 = *(const float4*)(bb);
            float4 g1 = *(const float4*)(bb + 8);
            float4 g2 = *(const float4*)(bb + 16);
            float4 g3 = *(const float4*)(bb + 24);
#pragma unroll
            for (int qt = 0; qt < 2; ++qt) {
                floatx16 st;
                st[0] = g0.x;  st[1] = g0.y;  st[2] = g0.z;  st[3] = g0.w;
                st[4] = g1.x;  st[5] = g1.y;  st[6] = g1.z;  st[7] = g1.w;
                st[8] = g2.x;  st[9] = g2.y;  st[10] = g2.z; st[11] = g2.w;
                st[12] = g3.x; st[13] = g3.y; st[14] = g3.z; st[15] = g3.w;
#pragma unroll
                for (int m = 0; m < 4; m++)
                    st = __builtin_amdgcn_mfma_f32_32x32x16_bf16(kf[m], qf[qt][m], st, 0, 0, 0);
                float xx[16];
#pragma unroll
                for (int r = 0; r < 16; r++) xx[r] = fexp2(st[r]);
                float2v a0 = {xx[0], xx[1]},  a1 = {xx[2], xx[3]};
                float2v a2 = {xx[4], xx[5]},  a3 = {xx[6], xx[7]};
                float2v a4 = {xx[8], xx[9]},  a5 = {xx[10], xx[11]};
                float2v a6 = {xx[12], xx[13]}, a7 = {xx[14], xx[15]};
                a0 += a1; a2 += a3; a4 += a5; a6 += a7;
                a0 += a2; a4 += a6;
                a0 += a4;
                rs[qt] += a0[0] + a0[1];
                uint32_t w00 = pk2(xx[0], xx[1]),   w01 = pk2(xx[2], xx[3]);
                uint32_t w10 = pk2(xx[4], xx[5]),   w11 = pk2(xx[6], xx[7]);
                uint32_t w20 = pk2(xx[8], xx[9]),   w21 = pk2(xx[10], xx[11]);
                uint32_t w30 = pk2(xx[12], xx[13]), w31 = pk2(xx[14], xx[15]);
                plswap(w00, w10); plswap(w01, w11);
                plswap(w20, w30); plswap(w21, w31);
                uintx4 t0 = {w00, w01, w10, w11};
                uintx4 t1 = {w20, w21, w30, w31};
                short8 bf0 = __builtin_bit_cast(short8, t0);
                short8 bf1 = __builtin_bit_cast(short8, t1);
                O[qt][0] = __builtin_amdgcn_mfma_f32_32x32x16_bf16(vf[0][0], bf0, O[qt][0], 0, 0, 0);
                O[qt][0] = __builtin_amdgcn_mfma_f32_32x32x16_bf16(vf[0][1], bf1, O[qt][0], 0, 0, 0);
                O[qt][1] = __builtin_amdgcn_mfma_f32_32x32x16_bf16(vf[1][0], bf0, O[qt][1], 0, 0, 0);
                O[qt][1] = __builtin_amdgcn_mfma_f32_32x32x16_bf16(vf[1][1], bf1, O[qt][1], 0, 0, 0);
            }
        }
    };

    stage(0);
    stage(1);
    // tiles 0..29 hand-unrolled x3; stage tiles 2..31; then peel 30/31.
#pragma unroll 1
    for (int t3 = 0; t3 < 10; ++t3) {
        WAITV(5); stage(2); compute(0);   // t = 3k
        WAITV(5); stage(0); compute(1);   // t = 3k+1
        WAITV(5); stage(1); compute(2);   // t = 3k+2
    }
    WAITV(5); compute(0);                 // tile 30
    WAITV(0); compute(1);                 // tile 31
    __syncthreads();                      // all K/V/B reads done before overlay

    // partial row-sums + partial O (raw, bf16) per q-tile
#pragma unroll
    for (int qt = 0; qt < 2; ++qt) {
        float r = rs[qt];
        r += __shfl_xor(r, 32);
        if (hf == 0)
            rsws[((size_t)kz * kBH + bh) * kS + qbase + qt * 32 + q32] = r;
        u16* Ob = ows + (((size_t)kz * kBH + bh) * kS + qbase + qt * 32) * kDk;
#pragma unroll
        for (int ds = 0; ds < 2; ds++) {
#pragma unroll
            for (int rr = 0; rr < 16; rr++)
                sm.ep[wv][q32][(rr & 3) + 8 * (rr >> 2) + 4 * hf] = O[qt][ds][rr];
            __builtin_amdgcn_wave_barrier();
            {
                const int qq = l >> 1, c0 = (l & 1) * 16;
                float f[16];
#pragma unroll
                for (int j = 0; j < 16; j++) f[j] = sm.ep[wv][qq][c0 + j];
                uint4 o0, o1;
                o0.x = pk2(f[0], f[1]);   o0.y = pk2(f[2], f[3]);
                o0.z = pk2(f[4], f[5]);   o0.w = pk2(f[6], f[7]);
                o1.x = pk2(f[8], f[9]);   o1.y = pk2(f[10], f[11]);
                o1.z = pk2(f[12], f[13]); o1.w = pk2(f[14], f[15]);
                u16* dp = Ob + (size_t)qq * kDk + ds * 32 + c0;
                *(uint4*)dp = o0;
                *(uint4*)(dp + 8) = o1;
            }
            __builtin_amdgcn_wave_barrier();
        }
    }
}

// ---- combine: out = (O_part0 + O_part1) / (rs0 + rs1), bf16 ---------------
__global__ __launch_bounds__(256) void combine(const u16* __restrict__ ows,
    const float* __restrict__ rsws, u16* __restrict__ xo) {
    size_t i = (size_t)blockIdx.x * 256 + threadIdx.x;   // 524288 total
    const int d8 = (int)(i & 7);
    const int s  = (int)((i >> 3) & (kS - 1));
    const int bh = (int)(i >> 15);
    const int b = bh >> 3, h = bh & 7;
    const size_t base = ((size_t)bh * kS + s) * kDk + d8 * 8;
    short8 a = *(const short8*)(ows + base);
    short8 c = *(const short8*)(ows + (size_t)kBH * kS * kDk + base);
    float r = rsws[(size_t)bh * kS + s] + rsws[(size_t)kBH * kS + (size_t)bh * kS + s];
    float inv = 1.0f / r;
    float e[8];
#pragma unroll
    for (int j = 0; j < 8; j++)
        e[j] = (bf2f((u16)a[j]) + bf2f((u16)c[j])) * inv;
    uint4 o;
    o.x = pk2(e[0], e[1]); o.y = pk2(e[2], e[3]);
    o.z = pk2(e[4], e[5]); o.w = pk2(e[6], e[7]);
    *(uint4*)(xo + ((size_t)b * kS + s) * kHid + h * 64 + d8 * 8) = o;
}

// ---- output projection: out = X @ Wo^T; 64x128 tile, BK=32 3-deep ----------
// (rolled rotation; v21-proven)
__global__ __launch_bounds__(256, 2) void oproj(const u16* __restrict__ x,
    const u16* __restrict__ w, float* __restrict__ out) {
    __shared__ __align__(16) u16 A[3][64][32];    // 12288 B
    __shared__ __align__(16) u16 Bt[3][128][32];  // 24576 B
    const int tid = threadIdx.x;
    const int wv = tid >> 6, lane = tid & 63;
    const int quad = lane >> 4, l16 = lane & 15;
    const int mb = blockIdx.x * 64, nb = blockIdx.y * 128;
    const int mw = (wv >> 1) * 32, nw = (wv & 1) * 64;
    floatx4 acc[2][4] = {};
    const int srow = lane >> 2;
    const int scol = ((lane & 3) ^ (srow & 3)) * 8;
    const u16* pA = x + (size_t)(mb + wv * 16 + srow) * kHid + scol;
    const u16* pB = w + (size_t)(nb + wv * 16 + srow) * kHid + scol;
    auto stage = [&](int buf) {
        gload16(pA,                     &A[buf][wv * 16][0]);
        gload16(pB,                     &Bt[buf][wv * 16][0]);
        gload16(pB + (size_t)64 * kHid, &Bt[buf][64 + wv * 16][0]);
        pA += 32; pB += 32;
    };
    auto compute = [&](int buf) {
        short8 a[2], bt[4];
#pragma unroll
        for (int i = 0; i < 2; i++)
            a[i] = *(const short8*)&A[buf][mw + i * 16 + l16][(quad ^ (l16 & 3)) * 8];
#pragma unroll
        for (int t = 0; t < 4; t++)
            bt[t] = *(const short8*)&Bt[buf][nw + t * 16 + l16][(quad ^ (l16 & 3)) * 8];
#pragma unroll
        for (int i = 0; i < 2; i++)
#pragma unroll
        for (int t = 0; t < 4; t++)
            acc[i][t] = __builtin_amdgcn_mfma_f32_16x16x32_bf16(a[i], bt[t], acc[i][t], 0, 0, 0);
    };

    stage(0);
    stage(1);
    for (int t = 0; t < 14; ++t) {
        WAITV(3);
        stage((t + 2) % 3);
        compute(t % 3);
    }
    WAITV(3);
    compute(2);                         // tile 14
    WAITV(0);
    compute(0);                         // tile 15

    const int mbw = mb + mw, nbw = nb + nw;
#pragma unroll
    for (int i = 0; i < 2; i++)
#pragma unroll
    for (int t = 0; t < 4; t++)
#pragma unroll
    for (int r = 0; r < 4; r++) {
        int m = mbw + i * 16 + quad * 4 + r;
        int n = nbw + t * 16 + l16;
        out[(size_t)m * kHid + n] = acc[i][t][r];
    }
}

} // namespace

extern "C" void kernel_launch(void* const* d_in, const int* in_sizes, int n_in,
                              void* d_out, int out_size, void* d_ws, size_t ws_size,
                              hipStream_t stream) {
    const float* q  = (const float*)d_in[0];
    const float* k  = (const float*)d_in[1];
    const float* v  = (const float*)d_in[2];
    const int* mask = (const int*)d_in[3];
    const float* w0 = (const float*)d_in[4];
    const float* w1 = (const float*)d_in[5];
    const float* w2 = (const float*)d_in[6];
    const float* w3 = (const float*)d_in[7];
    float* out = (float*)d_out;

    // ws (u16 units), ~52.4 MB:
    //   xall: 3*kM*kHid = 25.2 MB (bf16 q/k/v; reused as ows
    //         [2][16][4096][64] bf16 = 16.8 MB after proj)
    //   wall: 4*kHid*kHid = 2.1 MB (bf16 w0..w3; w0..w2 dead after proj ->
    //         rsws ([2][16][4096] f32, 512 KB); w3 stays live for oproj)
    //   qp, kp, vt: 8.4 MB each; xo (combine output) reuses qp after attn.
    // fbias (32 KB f32) lives in d_out scratch: written by cvt_qw, read by
    // attn, overwritten by oproj (which runs strictly after attn).
    u16* ws   = (u16*)d_ws;
    u16* xall = ws;
    u16* wall = xall + (size_t)3 * kM * kHid;
    u16* qp   = wall + (size_t)4 * kHid * kHid;
    u16* kp   = qp + (size_t)kBH * kS * kDk;
    u16* vt   = kp + (size_t)kBH * kS * kDk;
    u16* ows  = xall;
    float* rsws  = (float*)wall;
    float* fbias = out;
    u16* xo   = qp;

    dim3 blk(256);
    cvt_qw <<<dim3(13344), blk, 0, stream>>>(q, k, v, w0, w1, w2, w3, mask,
                                             xall, wall, fbias);
    proj   <<<dim3(kM / 128, kHid / 128, 3), blk, 0, stream>>>(xall, wall, qp, kp, vt);
    attn   <<<dim3(512), blk, 0, stream>>>(qp, kp, vt, fbias, ows, rsws);
    combine<<<dim3(2048), blk, 0, stream>>>(ows, rsws, xo);
    oproj  <<<dim3(kM / 64, kHid / 128), blk, 0, stream>>>(
        xo, wall + (size_t)3 * kHid * kHid, out);
}